// Round 1
// baseline (2407.061 us; speedup 1.0000x reference)
//
#include <hip/hip_runtime.h>
#include <math.h>

// Performer decoder layer, fp32. B=4, N=6400, D=256, H=8, K=32, M=8, DFF=1024.
// 7 fused dispatches:
//   memset(kv)
//   A1: QKV-proj + FAVOR phi   (x -> pq,pk,v)
//   B1: kv = pk^T v, psum = sum pk   (atomics)
//   C1: attn-combine + O-proj + residual + LN1 -> out1
//   A2/B2/C2: cross-attention (q from out1, k/v from enc)
//   D : FFN (elu) + residual + LN3 -> d_out
// All big GEMMs: 32-row A panel in LDS (full K=256), W in 16x256 LDS chunks,
// 8x4 register tile/thread, float4 everywhere. LN is wave-local (wave owns 8 rows).

#define NSEQ 6400

__device__ __forceinline__ void stage8k(const float* __restrict__ src, float* __restrict__ dst) {
    const int tid = threadIdx.x;
#pragma unroll
    for (int i = 0; i < 8; ++i)
        *(float4*)&dst[i * 1024 + tid * 4] = *(const float4*)&src[i * 1024 + tid * 4];
}

// acc[8][4] += A_lds[32x256] x W[256 x 256-col-slice]; W row stride ldw, cols at colbase.
// Internally barriers per 16-row W chunk; first barrier also orders caller's LDS writes.
__device__ __forceinline__ void gemm256(const float* __restrict__ W, int ldw, int colbase,
                                        const float* __restrict__ a_lds, float* __restrict__ w_lds,
                                        float (&acc)[8][4])
{
    const int tid = threadIdx.x;
    const int c0 = (tid & 63) * 4;
    const int rbase = (tid >> 6) * 8;
    for (int ch = 0; ch < 16; ++ch) {
        __syncthreads();  // protect w_lds from previous chunk's readers
#pragma unroll
        for (int i = 0; i < 4; ++i) {
            int j = i * 1024 + tid * 4;
            int wr = j >> 8, wc = j & 255;
            *(float4*)&w_lds[j] = *(const float4*)&W[(ch * 16 + wr) * ldw + colbase + wc];
        }
        __syncthreads();
#pragma unroll
        for (int kk = 0; kk < 16; kk += 4) {
            float4 w0 = *(const float4*)&w_lds[(kk + 0) * 256 + c0];
            float4 w1 = *(const float4*)&w_lds[(kk + 1) * 256 + c0];
            float4 w2 = *(const float4*)&w_lds[(kk + 2) * 256 + c0];
            float4 w3 = *(const float4*)&w_lds[(kk + 3) * 256 + c0];
#pragma unroll
            for (int r = 0; r < 8; ++r) {
                float4 av = *(const float4*)&a_lds[(rbase + r) * 256 + ch * 16 + kk];
                acc[r][0] += av.x * w0.x + av.y * w1.x + av.z * w2.x + av.w * w3.x;
                acc[r][1] += av.x * w0.y + av.y * w1.y + av.z * w2.y + av.w * w3.y;
                acc[r][2] += av.x * w0.z + av.y * w1.z + av.z * w2.z + av.w * w3.z;
                acc[r][3] += av.x * w0.w + av.y * w1.w + av.z * w2.w + av.w * w3.w;
            }
        }
    }
}

// wave-local LayerNorm over 256 cols (wave tr owns rows rbase..rbase+7), then store.
__device__ __forceinline__ void ln_store(float (&acc)[8][4], const float* __restrict__ g,
                                         const float* __restrict__ bb, float* __restrict__ out,
                                         int row0, int rbase, int c0)
{
    float4 gv = *(const float4*)&g[c0];
    float4 bv = *(const float4*)&bb[c0];
#pragma unroll
    for (int r = 0; r < 8; ++r) {
        float v0 = acc[r][0], v1 = acc[r][1], v2 = acc[r][2], v3 = acc[r][3];
        float s1 = v0 + v1 + v2 + v3;
        float s2 = v0 * v0 + v1 * v1 + v2 * v2 + v3 * v3;
#pragma unroll
        for (int off = 1; off < 64; off <<= 1) {
            s1 += __shfl_xor(s1, off);
            s2 += __shfl_xor(s2, off);
        }
        float mu = s1 * (1.0f / 256.0f);
        float var = fmaxf(s2 * (1.0f / 256.0f) - mu * mu, 0.0f);
        float rstd = rsqrtf(var + 1e-6f);
        float4 o;
        o.x = (v0 - mu) * rstd * gv.x + bv.x;
        o.y = (v1 - mu) * rstd * gv.y + bv.y;
        o.z = (v2 - mu) * rstd * gv.z + bv.z;
        o.w = (v3 - mu) * rstd * gv.w + bv.w;
        *(float4*)&out[(long)(row0 + rbase + r) * 256 + c0] = o;
    }
}

// ---------------- Kernel A: QKV projection + phi ----------------
__global__ __launch_bounds__(256) void qkv_phi_k(
    const float* __restrict__ qsrc, const float* __restrict__ kvsrc,
    const float* __restrict__ qw, const float* __restrict__ qb,
    const float* __restrict__ kw, const float* __restrict__ kb,
    const float* __restrict__ vw, const float* __restrict__ vb,
    const float* __restrict__ feat,
    float* __restrict__ pq,   // [25600][64]   ([b][n][h][m])
    float* __restrict__ pk,   // [B][H][N][8]
    float* __restrict__ vout) // [25600][256]  ([b][n][h*32+k])
{
    __shared__ float a_s[32 * 256];
    __shared__ float w_s[16 * 256];
    __shared__ float feat_s[32 * 9];  // padded rows: stride 9 avoids bank conflict w/ rotation
    const int tid = threadIdx.x;
    const int row0 = blockIdx.x * 32;
    const int b = row0 / NSEQ;
    const int n0 = row0 % NSEQ;
    const int c0 = (tid & 63) * 4, rbase = (tid >> 6) * 8;
    {
        int k = tid >> 3, m = tid & 7;
        feat_s[k * 9 + m] = feat[tid];   // feat is [32][8] = 256 elems
    }
    stage8k(qsrc + (long)row0 * 256, a_s);
    __syncthreads();
    const float qscale = 0.42044820762685725f;  // 32^-0.25
    const float phin = 0.35355339059327373f;    // 1/sqrt(8)
    float acc[8][4];

    // ---------- Q pass ----------
    {
        float4 bv = *(const float4*)&qb[c0];
#pragma unroll
        for (int r = 0; r < 8; ++r) { acc[r][0] = bv.x; acc[r][1] = bv.y; acc[r][2] = bv.z; acc[r][3] = bv.w; }
    }
    gemm256(qw, 256, 0, a_s, w_s, acc);
    __syncthreads();  // all a_s readers done -> safe to overwrite with q
#pragma unroll
    for (int r = 0; r < 8; ++r) {
        float4 t = make_float4(acc[r][0] * qscale, acc[r][1] * qscale, acc[r][2] * qscale, acc[r][3] * qscale);
        *(float4*)&a_s[(rbase + r) * 256 + c0] = t;
    }
    __syncthreads();
    // phi(q) -> pq. 2048 tasks (32 rows x 8 h x 8 m), 8/thread; rotated k avoids 8-way conflict.
#pragma unroll
    for (int i = 0; i < 8; ++i) {
        int T = tid + 256 * i;
        int r = T >> 6, h = (T >> 3) & 7, m = T & 7;
        float dot = 0.f, nrm = 0.f;
#pragma unroll
        for (int k = 0; k < 32; ++k) {
            int kk = (k + 4 * h) & 31;
            float qv = a_s[r * 256 + h * 32 + kk];
            dot += qv * feat_s[kk * 9 + m];
            nrm += qv * qv;
        }
        pq[(long)row0 * 64 + T] = expf(dot - 0.5f * nrm) * phin;  // T == r*64 + h*8 + m
    }
    __syncthreads();

    // ---------- K pass ----------
    stage8k(kvsrc + (long)row0 * 256, a_s);  // gemm's first barrier orders these writes
    {
        float4 bv = *(const float4*)&kb[c0];
#pragma unroll
        for (int r = 0; r < 8; ++r) { acc[r][0] = bv.x; acc[r][1] = bv.y; acc[r][2] = bv.z; acc[r][3] = bv.w; }
    }
    gemm256(kw, 256, 0, a_s, w_s, acc);
    __syncthreads();
#pragma unroll
    for (int r = 0; r < 8; ++r) {
        float4 t = make_float4(acc[r][0] * qscale, acc[r][1] * qscale, acc[r][2] * qscale, acc[r][3] * qscale);
        *(float4*)&a_s[(rbase + r) * 256 + c0] = t;
    }
    __syncthreads();
#pragma unroll
    for (int i = 0; i < 8; ++i) {
        int T = tid + 256 * i;
        int r = T >> 6, h = (T >> 3) & 7, m = T & 7;
        float dot = 0.f, nrm = 0.f;
#pragma unroll
        for (int k = 0; k < 32; ++k) {
            int kk = (k + 4 * h) & 31;
            float qv = a_s[r * 256 + h * 32 + kk];
            dot += qv * feat_s[kk * 9 + m];
            nrm += qv * qv;
        }
        pk[((long)(b * 8 + h) * NSEQ + n0 + r) * 8 + m] = expf(dot - 0.5f * nrm) * phin;
    }
    __syncthreads();

    // ---------- V pass ----------
    stage8k(kvsrc + (long)row0 * 256, a_s);
    {
        float4 bv = *(const float4*)&vb[c0];
#pragma unroll
        for (int r = 0; r < 8; ++r) { acc[r][0] = bv.x; acc[r][1] = bv.y; acc[r][2] = bv.z; acc[r][3] = bv.w; }
    }
    gemm256(vw, 256, 0, a_s, w_s, acc);
#pragma unroll
    for (int r = 0; r < 8; ++r) {
        float4 t = make_float4(acc[r][0], acc[r][1], acc[r][2], acc[r][3]);
        *(float4*)&vout[(long)(row0 + rbase + r) * 256 + c0] = t;
    }
}

// ---------------- Kernel B: kv = sum_n pk outer v ; psum = sum_n pk ----------------
__global__ __launch_bounds__(256) void kv_reduce_k(
    const float* __restrict__ pk,  // [B][H][N][8]
    const float* __restrict__ v,   // [25600][256]
    float* __restrict__ kvg,       // [B][H][8][32] (zeroed)
    float* __restrict__ psg)       // [B][H][8]     (zeroed)
{
    const int blk = blockIdx.x;     // 32 bh * 25 chunks
    const int bh = blk / 25, ch = blk % 25;
    const int b = bh >> 3, h = bh & 7;
    const int n0 = ch * 256;
    const int tid = threadIdx.x;
    const int m = tid >> 5, k = tid & 31;
    const float* pkp = pk + ((long)bh * NSEQ + n0) * 8 + m;
    const float* vp = v + ((long)b * NSEQ + n0) * 256 + h * 32 + k;
    float acc = 0.f, ps = 0.f;
#pragma unroll 4
    for (int n = 0; n < 256; ++n) {
        float pkv = pkp[n * 8];
        float vv = vp[n * 256];
        acc += pkv * vv;
        ps += pkv;
    }
    atomicAdd(&kvg[(bh * 8 + m) * 32 + k], acc);
    if (k == 0) atomicAdd(&psg[bh * 8 + m], ps);
}

// ---------------- Kernel C: attn combine + O-proj + residual + LN ----------------
__global__ __launch_bounds__(256) void attn_out_ln_k(
    const float* __restrict__ pq,   // [25600][64]
    const float* __restrict__ kvg,  // [B][H][8][32]
    const float* __restrict__ psg,  // [B][H][8]
    const float* __restrict__ ow, const float* __restrict__ ob,
    const float* __restrict__ resid,
    const float* __restrict__ g, const float* __restrict__ bb,
    float* __restrict__ out)
{
    __shared__ float pq_s[32 * 64];
    __shared__ float kv_s[2048];
    __shared__ float ps_s[64];
    __shared__ float z_s[32 * 8];
    __shared__ float attn_s[32 * 256];
    __shared__ float w_s[16 * 256];
    const int tid = threadIdx.x;
    const int row0 = blockIdx.x * 32;
    const int b = row0 / NSEQ;
    const int c0 = (tid & 63) * 4, rbase = (tid >> 6) * 8;

    *(float4*)&pq_s[tid * 8] = *(const float4*)&pq[(long)row0 * 64 + tid * 8];
    *(float4*)&pq_s[tid * 8 + 4] = *(const float4*)&pq[(long)row0 * 64 + tid * 8 + 4];
    *(float4*)&kv_s[tid * 8] = *(const float4*)&kvg[b * 2048 + tid * 8];
    *(float4*)&kv_s[tid * 8 + 4] = *(const float4*)&kvg[b * 2048 + tid * 8 + 4];
    if (tid < 16) *(float4*)&ps_s[tid * 4] = *(const float4*)&psg[b * 64 + tid * 4];
    __syncthreads();

    {   // z = 1/(pq . psum + eps): 256 tasks (32 rows x 8 heads)
        int r = tid >> 3, h = tid & 7;
        float d = 1e-6f;
#pragma unroll
        for (int m = 0; m < 8; ++m) d += pq_s[r * 64 + h * 8 + m] * ps_s[h * 8 + m];
        z_s[r * 8 + h] = 1.0f / d;
    }
    __syncthreads();
    {   // attn[r][c] = z * (pq_row . kv[:,k]); thread owns column c for all 32 rows
        int c = tid, h = c >> 5, k = c & 31;
        float kvv[8];
#pragma unroll
        for (int m = 0; m < 8; ++m) kvv[m] = kv_s[(h * 8 + m) * 32 + k];
        for (int r = 0; r < 32; ++r) {
            float d = 0.f;
#pragma unroll
            for (int m = 0; m < 8; ++m) d += pq_s[r * 64 + h * 8 + m] * kvv[m];
            attn_s[r * 256 + c] = d * z_s[r * 8 + h];
        }
    }
    float acc[8][4];
    {
        float4 bv = *(const float4*)&ob[c0];
#pragma unroll
        for (int r = 0; r < 8; ++r) {
            float4 rv = *(const float4*)&resid[(long)(row0 + rbase + r) * 256 + c0];
            acc[r][0] = bv.x + rv.x; acc[r][1] = bv.y + rv.y;
            acc[r][2] = bv.z + rv.z; acc[r][3] = bv.w + rv.w;
        }
    }
    gemm256(ow, 256, 0, attn_s, w_s, acc);  // first barrier orders attn_s writes
    ln_store(acc, g, bb, out, row0, rbase, c0);
}

// ---------------- Kernel D: FFN (elu) + residual + LN3 ----------------
__global__ __launch_bounds__(256) void ffn_ln_k(
    const float* __restrict__ in,   // out2
    const float* __restrict__ w1, const float* __restrict__ b1,
    const float* __restrict__ w2, const float* __restrict__ b2,
    const float* __restrict__ g, const float* __restrict__ bb,
    float* __restrict__ out)
{
    __shared__ float a_s[32 * 256];
    __shared__ float h_s[32 * 256];
    __shared__ float w_s[16 * 256];
    const int tid = threadIdx.x;
    const int row0 = blockIdx.x * 32;
    const int c0 = (tid & 63) * 4, rbase = (tid >> 6) * 8;
    stage8k(in + (long)row0 * 256, a_s);
    __syncthreads();
    float oacc[8][4];
    {
        float4 bv = *(const float4*)&b2[c0];
#pragma unroll
        for (int r = 0; r < 8; ++r) {
            float4 rv = *(const float4*)&a_s[(rbase + r) * 256 + c0];
            oacc[r][0] = bv.x + rv.x; oacc[r][1] = bv.y + rv.y;
            oacc[r][2] = bv.z + rv.z; oacc[r][3] = bv.w + rv.w;
        }
    }
    for (int fc = 0; fc < 4; ++fc) {
        float hacc[8][4];
        float4 bv = *(const float4*)&b1[fc * 256 + c0];
#pragma unroll
        for (int r = 0; r < 8; ++r) { hacc[r][0] = bv.x; hacc[r][1] = bv.y; hacc[r][2] = bv.z; hacc[r][3] = bv.w; }
        gemm256(w1, 1024, fc * 256, a_s, w_s, hacc);     // h chunk = out2 @ w1[:, fc*256:+256]
        __syncthreads();
#pragma unroll
        for (int r = 0; r < 8; ++r) {
            float4 t;
            t.x = hacc[r][0] > 0.f ? hacc[r][0] : expm1f(hacc[r][0]);
            t.y = hacc[r][1] > 0.f ? hacc[r][1] : expm1f(hacc[r][1]);
            t.z = hacc[r][2] > 0.f ? hacc[r][2] : expm1f(hacc[r][2]);
            t.w = hacc[r][3] > 0.f ? hacc[r][3] : expm1f(hacc[r][3]);
            *(float4*)&h_s[(rbase + r) * 256 + c0] = t;
        }
        gemm256(w2 + (long)fc * 256 * 256, 256, 0, h_s, w_s, oacc);  // partial h @ w2
    }
    ln_store(oacc, g, bb, out, row0, rbase, c0);
}

extern "C" void kernel_launch(void* const* d_in, const int* in_sizes, int n_in,
                              void* d_out, int out_size, void* d_ws, size_t ws_size,
                              hipStream_t stream)
{
    const float* x = (const float*)d_in[0];
    const float* enc = (const float*)d_in[1];
    const float* m1_qw = (const float*)d_in[2];
    const float* m1_qb = (const float*)d_in[3];
    const float* m1_kw = (const float*)d_in[4];
    const float* m1_kb = (const float*)d_in[5];
    const float* m1_vw = (const float*)d_in[6];
    const float* m1_vb = (const float*)d_in[7];
    const float* m1_ow = (const float*)d_in[8];
    const float* m1_ob = (const float*)d_in[9];
    const float* m1_feat = (const float*)d_in[10];
    const float* m2_qw = (const float*)d_in[11];
    const float* m2_qb = (const float*)d_in[12];
    const float* m2_kw = (const float*)d_in[13];
    const float* m2_kb = (const float*)d_in[14];
    const float* m2_vw = (const float*)d_in[15];
    const float* m2_vb = (const float*)d_in[16];
    const float* m2_ow = (const float*)d_in[17];
    const float* m2_ob = (const float*)d_in[18];
    const float* m2_feat = (const float*)d_in[19];
    const float* ffn_w1 = (const float*)d_in[20];
    const float* ffn_b1 = (const float*)d_in[21];
    const float* ffn_w2 = (const float*)d_in[22];
    const float* ffn_b2 = (const float*)d_in[23];
    const float* ln1_g = (const float*)d_in[24];
    const float* ln1_b = (const float*)d_in[25];
    const float* ln2_g = (const float*)d_in[26];
    const float* ln2_b = (const float*)d_in[27];
    const float* ln3_g = (const float*)d_in[28];
    const float* ln3_b = (const float*)d_in[29];

    float* ws = (float*)d_ws;
    float* pq = ws;                        // 25600*64   = 1,638,400
    float* pk = pq + 1638400;              // 1,638,400
    float* v = pk + 1638400;               // 25600*256  = 6,553,600
    float* kv1 = v + 6553600;              // 8192
    float* ps1 = kv1 + 8192;               // 256
    float* kv2 = ps1 + 256;                // 8192
    float* ps2 = kv2 + 8192;               // 256
    float* out1 = ps2 + 256;               // 6,553,600
    float* out2 = out1 + 6553600;          // 6,553,600
    float* out3 = (float*)d_out;

    hipMemsetAsync(kv1, 0, (8192 + 256) * 2 * sizeof(float), stream);

    // self-attention
    qkv_phi_k<<<800, 256, 0, stream>>>(x, x, m1_qw, m1_qb, m1_kw, m1_kb, m1_vw, m1_vb,
                                       m1_feat, pq, pk, v);
    kv_reduce_k<<<800, 256, 0, stream>>>(pk, v, kv1, ps1);
    attn_out_ln_k<<<800, 256, 0, stream>>>(pq, kv1, ps1, m1_ow, m1_ob, x, ln1_g, ln1_b, out1);
    // cross-attention (q from out1, k/v from encoder)
    qkv_phi_k<<<800, 256, 0, stream>>>(out1, enc, m2_qw, m2_qb, m2_kw, m2_kb, m2_vw, m2_vb,
                                       m2_feat, pq, pk, v);
    kv_reduce_k<<<800, 256, 0, stream>>>(pk, v, kv2, ps2);
    attn_out_ln_k<<<800, 256, 0, stream>>>(pq, kv2, ps2, m2_ow, m2_ob, out1, ln2_g, ln2_b, out2);
    // FFN
    ffn_ln_k<<<800, 256, 0, stream>>>(out2, ffn_w1, ffn_b1, ffn_w2, ffn_b2, ln3_g, ln3_b, out3);
}

// Round 7
// 1471.066 us; speedup vs baseline: 1.6363x; 1.6363x over previous
//
#include <hip/hip_runtime.h>
#include <math.h>

// Round 7: bisection build, layout-fixed.
// Attention path (both performer modules) = round-1 kernels VERBATIM (proven pass).
// FFN = fused MFMA kernel (single-bf16 16x16x32) + weight-pack kernel.
// ws layout = round-1's exact proven layout (91.8 MB). FFN packs live in pq's
// region and prep_w runs AFTER module 2 (pq dead by then), right before ffn_k.

#define NSEQ 6400

typedef __attribute__((ext_vector_type(8))) short bf16x8;
typedef __attribute__((ext_vector_type(4))) float f32x4;

__device__ __forceinline__ unsigned short f2bf(float f) {
    unsigned u = __float_as_uint(f);
    return (unsigned short)((u + 0x7fffu + ((u >> 16) & 1u)) >> 16);
}

__device__ __forceinline__ bf16x8 frag_ld(const unsigned short* __restrict__ p) {
    union { uint2 u[2]; bf16x8 v; } x;
    x.u[0] = *(const uint2*)&p[0];
    x.u[1] = *(const uint2*)&p[4];
    return x.v;
}

// ================= round-1 proven attention-path kernels (verbatim) =================

__device__ __forceinline__ void stage8k(const float* __restrict__ src, float* __restrict__ dst) {
    const int tid = threadIdx.x;
#pragma unroll
    for (int i = 0; i < 8; ++i)
        *(float4*)&dst[i * 1024 + tid * 4] = *(const float4*)&src[i * 1024 + tid * 4];
}

__device__ __forceinline__ void gemm256(const float* __restrict__ W, int ldw, int colbase,
                                        const float* __restrict__ a_lds, float* __restrict__ w_lds,
                                        float (&acc)[8][4])
{
    const int tid = threadIdx.x;
    const int c0 = (tid & 63) * 4;
    const int rbase = (tid >> 6) * 8;
    for (int ch = 0; ch < 16; ++ch) {
        __syncthreads();
#pragma unroll
        for (int i = 0; i < 4; ++i) {
            int j = i * 1024 + tid * 4;
            int wr = j >> 8, wc = j & 255;
            *(float4*)&w_lds[j] = *(const float4*)&W[(ch * 16 + wr) * ldw + colbase + wc];
        }
        __syncthreads();
#pragma unroll
        for (int kk = 0; kk < 16; kk += 4) {
            float4 w0 = *(const float4*)&w_lds[(kk + 0) * 256 + c0];
            float4 w1 = *(const float4*)&w_lds[(kk + 1) * 256 + c0];
            float4 w2 = *(const float4*)&w_lds[(kk + 2) * 256 + c0];
            float4 w3 = *(const float4*)&w_lds[(kk + 3) * 256 + c0];
#pragma unroll
            for (int r = 0; r < 8; ++r) {
                float4 av = *(const float4*)&a_lds[(rbase + r) * 256 + ch * 16 + kk];
                acc[r][0] += av.x * w0.x + av.y * w1.x + av.z * w2.x + av.w * w3.x;
                acc[r][1] += av.x * w0.y + av.y * w1.y + av.z * w2.y + av.w * w3.y;
                acc[r][2] += av.x * w0.z + av.y * w1.z + av.z * w2.z + av.w * w3.z;
                acc[r][3] += av.x * w0.w + av.y * w1.w + av.z * w2.w + av.w * w3.w;
            }
        }
    }
}

__device__ __forceinline__ void ln_store(float (&acc)[8][4], const float* __restrict__ g,
                                         const float* __restrict__ bb, float* __restrict__ out,
                                         int row0, int rbase, int c0)
{
    float4 gv = *(const float4*)&g[c0];
    float4 bv = *(const float4*)&bb[c0];
#pragma unroll
    for (int r = 0; r < 8; ++r) {
        float v0 = acc[r][0], v1 = acc[r][1], v2 = acc[r][2], v3 = acc[r][3];
        float s1 = v0 + v1 + v2 + v3;
        float s2 = v0 * v0 + v1 * v1 + v2 * v2 + v3 * v3;
#pragma unroll
        for (int off = 1; off < 64; off <<= 1) {
            s1 += __shfl_xor(s1, off);
            s2 += __shfl_xor(s2, off);
        }
        float mu = s1 * (1.0f / 256.0f);
        float var = fmaxf(s2 * (1.0f / 256.0f) - mu * mu, 0.0f);
        float rstd = rsqrtf(var + 1e-6f);
        float4 o;
        o.x = (v0 - mu) * rstd * gv.x + bv.x;
        o.y = (v1 - mu) * rstd * gv.y + bv.y;
        o.z = (v2 - mu) * rstd * gv.z + bv.z;
        o.w = (v3 - mu) * rstd * gv.w + bv.w;
        *(float4*)&out[(long)(row0 + rbase + r) * 256 + c0] = o;
    }
}

__global__ __launch_bounds__(256) void qkv_phi_k(
    const float* __restrict__ qsrc, const float* __restrict__ kvsrc,
    const float* __restrict__ qw, const float* __restrict__ qb,
    const float* __restrict__ kw, const float* __restrict__ kb,
    const float* __restrict__ vw, const float* __restrict__ vb,
    const float* __restrict__ feat,
    float* __restrict__ pq,   // [25600][64]
    float* __restrict__ pk,   // [B][H][N][8]
    float* __restrict__ vout) // [25600][256]
{
    __shared__ float a_s[32 * 256];
    __shared__ float w_s[16 * 256];
    __shared__ float feat_s[32 * 9];
    const int tid = threadIdx.x;
    const int row0 = blockIdx.x * 32;
    const int b = row0 / NSEQ;
    const int n0 = row0 % NSEQ;
    const int c0 = (tid & 63) * 4, rbase = (tid >> 6) * 8;
    {
        int k = tid >> 3, m = tid & 7;
        feat_s[k * 9 + m] = feat[tid];
    }
    stage8k(qsrc + (long)row0 * 256, a_s);
    __syncthreads();
    const float qscale = 0.42044820762685725f;
    const float phin = 0.35355339059327373f;
    float acc[8][4];

    // Q pass
    {
        float4 bv = *(const float4*)&qb[c0];
#pragma unroll
        for (int r = 0; r < 8; ++r) { acc[r][0] = bv.x; acc[r][1] = bv.y; acc[r][2] = bv.z; acc[r][3] = bv.w; }
    }
    gemm256(qw, 256, 0, a_s, w_s, acc);
    __syncthreads();
#pragma unroll
    for (int r = 0; r < 8; ++r) {
        float4 t = make_float4(acc[r][0] * qscale, acc[r][1] * qscale, acc[r][2] * qscale, acc[r][3] * qscale);
        *(float4*)&a_s[(rbase + r) * 256 + c0] = t;
    }
    __syncthreads();
#pragma unroll
    for (int i = 0; i < 8; ++i) {
        int T = tid + 256 * i;
        int r = T >> 6, h = (T >> 3) & 7, m = T & 7;
        float dot = 0.f, nrm = 0.f;
#pragma unroll
        for (int k = 0; k < 32; ++k) {
            int kk = (k + 4 * h) & 31;
            float qv = a_s[r * 256 + h * 32 + kk];
            dot += qv * feat_s[kk * 9 + m];
            nrm += qv * qv;
        }
        pq[(long)row0 * 64 + T] = expf(dot - 0.5f * nrm) * phin;
    }
    __syncthreads();

    // K pass
    stage8k(kvsrc + (long)row0 * 256, a_s);
    {
        float4 bv = *(const float4*)&kb[c0];
#pragma unroll
        for (int r = 0; r < 8; ++r) { acc[r][0] = bv.x; acc[r][1] = bv.y; acc[r][2] = bv.z; acc[r][3] = bv.w; }
    }
    gemm256(kw, 256, 0, a_s, w_s, acc);
    __syncthreads();
#pragma unroll
    for (int r = 0; r < 8; ++r) {
        float4 t = make_float4(acc[r][0] * qscale, acc[r][1] * qscale, acc[r][2] * qscale, acc[r][3] * qscale);
        *(float4*)&a_s[(rbase + r) * 256 + c0] = t;
    }
    __syncthreads();
#pragma unroll
    for (int i = 0; i < 8; ++i) {
        int T = tid + 256 * i;
        int r = T >> 6, h = (T >> 3) & 7, m = T & 7;
        float dot = 0.f, nrm = 0.f;
#pragma unroll
        for (int k = 0; k < 32; ++k) {
            int kk = (k + 4 * h) & 31;
            float qv = a_s[r * 256 + h * 32 + kk];
            dot += qv * feat_s[kk * 9 + m];
            nrm += qv * qv;
        }
        pk[((long)(b * 8 + h) * NSEQ + n0 + r) * 8 + m] = expf(dot - 0.5f * nrm) * phin;
    }
    __syncthreads();

    // V pass
    stage8k(kvsrc + (long)row0 * 256, a_s);
    {
        float4 bv = *(const float4*)&vb[c0];
#pragma unroll
        for (int r = 0; r < 8; ++r) { acc[r][0] = bv.x; acc[r][1] = bv.y; acc[r][2] = bv.z; acc[r][3] = bv.w; }
    }
    gemm256(vw, 256, 0, a_s, w_s, acc);
#pragma unroll
    for (int r = 0; r < 8; ++r) {
        float4 t = make_float4(acc[r][0], acc[r][1], acc[r][2], acc[r][3]);
        *(float4*)&vout[(long)(row0 + rbase + r) * 256 + c0] = t;
    }
}

__global__ __launch_bounds__(256) void kv_reduce_k(
    const float* __restrict__ pk,
    const float* __restrict__ v,
    float* __restrict__ kvg,
    float* __restrict__ psg)
{
    const int blk = blockIdx.x;
    const int bh = blk / 25, ch = blk % 25;
    const int b = bh >> 3, h = bh & 7;
    const int n0 = ch * 256;
    const int tid = threadIdx.x;
    const int m = tid >> 5, k = tid & 31;
    const float* pkp = pk + ((long)bh * NSEQ + n0) * 8 + m;
    const float* vp = v + ((long)b * NSEQ + n0) * 256 + h * 32 + k;
    float acc = 0.f, ps = 0.f;
#pragma unroll 4
    for (int n = 0; n < 256; ++n) {
        float pkv = pkp[n * 8];
        float vv = vp[n * 256];
        acc += pkv * vv;
        ps += pkv;
    }
    atomicAdd(&kvg[(bh * 8 + m) * 32 + k], acc);
    if (k == 0) atomicAdd(&psg[bh * 8 + m], ps);
}

__global__ __launch_bounds__(256) void attn_out_ln_k(
    const float* __restrict__ pq,
    const float* __restrict__ kvg,
    const float* __restrict__ psg,
    const float* __restrict__ ow, const float* __restrict__ ob,
    const float* __restrict__ resid,
    const float* __restrict__ g, const float* __restrict__ bb,
    float* __restrict__ out)
{
    __shared__ float pq_s[32 * 64];
    __shared__ float kv_s[2048];
    __shared__ float ps_s[64];
    __shared__ float z_s[32 * 8];
    __shared__ float attn_s[32 * 256];
    __shared__ float w_s[16 * 256];
    const int tid = threadIdx.x;
    const int row0 = blockIdx.x * 32;
    const int b = row0 / NSEQ;
    const int c0 = (tid & 63) * 4, rbase = (tid >> 6) * 8;

    *(float4*)&pq_s[tid * 8] = *(const float4*)&pq[(long)row0 * 64 + tid * 8];
    *(float4*)&pq_s[tid * 8 + 4] = *(const float4*)&pq[(long)row0 * 64 + tid * 8 + 4];
    *(float4*)&kv_s[tid * 8] = *(const float4*)&kvg[b * 2048 + tid * 8];
    *(float4*)&kv_s[tid * 8 + 4] = *(const float4*)&kvg[b * 2048 + tid * 8 + 4];
    if (tid < 16) *(float4*)&ps_s[tid * 4] = *(const float4*)&psg[b * 64 + tid * 4];
    __syncthreads();

    {
        int r = tid >> 3, h = tid & 7;
        float d = 1e-6f;
#pragma unroll
        for (int m = 0; m < 8; ++m) d += pq_s[r * 64 + h * 8 + m] * ps_s[h * 8 + m];
        z_s[r * 8 + h] = 1.0f / d;
    }
    __syncthreads();
    {
        int c = tid, h = c >> 5, k = c & 31;
        float kvv[8];
#pragma unroll
        for (int m = 0; m < 8; ++m) kvv[m] = kv_s[(h * 8 + m) * 32 + k];
        for (int r = 0; r < 32; ++r) {
            float d = 0.f;
#pragma unroll
            for (int m = 0; m < 8; ++m) d += pq_s[r * 64 + h * 8 + m] * kvv[m];
            attn_s[r * 256 + c] = d * z_s[r * 8 + h];
        }
    }
    float acc[8][4];
    {
        float4 bv = *(const float4*)&ob[c0];
#pragma unroll
        for (int r = 0; r < 8; ++r) {
            float4 rv = *(const float4*)&resid[(long)(row0 + rbase + r) * 256 + c0];
            acc[r][0] = bv.x + rv.x; acc[r][1] = bv.y + rv.y;
            acc[r][2] = bv.z + rv.z; acc[r][3] = bv.w + rv.w;
        }
    }
    gemm256(ow, 256, 0, attn_s, w_s, acc);
    ln_store(acc, g, bb, out, row0, rbase, c0);
}

// ================= new FFN path: weight pack + fused MFMA FFN =================

// pack fp32 W[K][N] -> bf16 [K/32][N][32] (per 32-k chunk, n-major)
__global__ __launch_bounds__(256) void prep_w_k(
    const float* __restrict__ w1, const float* __restrict__ w2,
    unsigned short* __restrict__ w1h, unsigned short* __restrict__ w2h)
{
    __shared__ float wt[32][65];
    const int tid = threadIdx.x;
    const int id = blockIdx.x;
    const float* src; unsigned short* dh;
    int Nsrc, kc, nb;
    if (id < 128) {                 // ffn_w1 [256][1024]: 8 kc x 16 nb
        src = w1; dh = w1h; Nsrc = 1024;
        kc = id >> 4; nb = id & 15;
    } else {                        // ffn_w2 [1024][256]: 32 kc x 4 nb
        int lid = id - 128;
        src = w2; dh = w2h; Nsrc = 256;
        kc = lid >> 2; nb = lid & 3;
    }
    {
        int kr = tid >> 3, nc8 = (tid & 7) * 8;
        const float* sp = &src[(long)(kc * 32 + kr) * Nsrc + nb * 64 + nc8];
        float4 fa = *(const float4*)&sp[0], fb = *(const float4*)&sp[4];
        wt[kr][nc8 + 0] = fa.x; wt[kr][nc8 + 1] = fa.y; wt[kr][nc8 + 2] = fa.z; wt[kr][nc8 + 3] = fa.w;
        wt[kr][nc8 + 4] = fb.x; wt[kr][nc8 + 5] = fb.y; wt[kr][nc8 + 6] = fb.z; wt[kr][nc8 + 7] = fb.w;
    }
    __syncthreads();
    {
        int col = tid >> 2, part = tid & 3;
        unsigned short hh[8];
#pragma unroll
        for (int j = 0; j < 8; ++j) hh[j] = f2bf(wt[part * 8 + j][col]);
        long di = ((long)kc * Nsrc + nb * 64 + col) * 32 + part * 8;
        uint2 a, b;
        a.x = (unsigned)hh[0] | ((unsigned)hh[1] << 16); a.y = (unsigned)hh[2] | ((unsigned)hh[3] << 16);
        b.x = (unsigned)hh[4] | ((unsigned)hh[5] << 16); b.y = (unsigned)hh[6] | ((unsigned)hh[7] << 16);
        *(uint2*)&dh[di] = a;
        *(uint2*)&dh[di + 4] = b;
    }
}

// fused FFN1(elu)+FFN2 + residual + LN3, single-bf16 MFMA 16x16x32.
// 64-row tile, 4 waves x (4x4 frags of 16x16). h chunk lives in LDS bf16.
__global__ __launch_bounds__(256, 2) void ffn_k(
    const float* __restrict__ A,   // out2 [25600][256] fp32
    const unsigned short* __restrict__ W1h, const unsigned short* __restrict__ W2h,
    const float* __restrict__ b1, const float* __restrict__ b2,
    const float* __restrict__ lng, const float* __restrict__ lnb,
    float* __restrict__ out)
{
    __shared__ unsigned short As[64 * 36];    // [row][k] bf16, stride 36
    __shared__ unsigned short Ws[256 * 36];   // [col][k] bf16
    __shared__ unsigned short Hs[64 * 260];   // h chunk [row][256], stride 260
    __shared__ float red1[64][5];
    __shared__ float red2[64][5];
    const int tid = threadIdx.x;
    const int row0 = blockIdx.x * 64;
    const int w = tid >> 6, lane = tid & 63;
    const int l16 = lane & 15, kg = lane >> 4;
    const int st_row = tid >> 2, st_part = tid & 3;

    f32x4 oacc[4][4];
#pragma unroll
    for (int ct = 0; ct < 4; ++ct) {
        int col = w * 64 + ct * 16 + l16;
        float bv = b2[col];
#pragma unroll
        for (int rt = 0; rt < 4; ++rt)
#pragma unroll
            for (int reg = 0; reg < 4; ++reg) {
                int row = row0 + rt * 16 + kg * 4 + reg;
                oacc[rt][ct][reg] = bv + A[(long)row * 256 + col];
            }
    }

    for (int fc = 0; fc < 4; ++fc) {
        // ---- FFN1: hacc = A @ w1[:, fc*256 .. +256] ----
        f32x4 hacc[4][4];
#pragma unroll
        for (int ct = 0; ct < 4; ++ct) {
            float bv = b1[fc * 256 + w * 64 + ct * 16 + l16];
#pragma unroll
            for (int rt = 0; rt < 4; ++rt) hacc[rt][ct] = (f32x4)(bv);
        }
        for (int kc = 0; kc < 8; ++kc) {
            __syncthreads();   // protect As/Ws from previous readers
            {   // stage A (fp32 -> single bf16)
                const float* sp = &A[(long)(row0 + st_row) * 256 + kc * 32 + st_part * 8];
                float f[8];
                *(float4*)&f[0] = *(const float4*)&sp[0];
                *(float4*)&f[4] = *(const float4*)&sp[4];
                unsigned short h8[8];
#pragma unroll
                for (int j = 0; j < 8; ++j) h8[j] = f2bf(f[j]);
                uint2 a, b;
                a.x = (unsigned)h8[0] | ((unsigned)h8[1] << 16); a.y = (unsigned)h8[2] | ((unsigned)h8[3] << 16);
                b.x = (unsigned)h8[4] | ((unsigned)h8[5] << 16); b.y = (unsigned)h8[6] | ((unsigned)h8[7] << 16);
                unsigned short* dp = &As[st_row * 36 + st_part * 8];
                *(uint2*)&dp[0] = a;
                *(uint2*)&dp[4] = b;
            }
#pragma unroll
            for (int i = 0; i < 4; ++i) {   // stage W1 chunk (pre-packed bf16)
                int idx = i * 256 + tid;
                int col = idx >> 2, part = idx & 3;
                long wsrc = ((long)kc * 1024 + fc * 256 + col) * 32 + part * 8;
                uint2 va = *(const uint2*)&W1h[wsrc];
                uint2 vb = *(const uint2*)&W1h[wsrc + 4];
                unsigned short* dp = &Ws[col * 36 + part * 8];
                *(uint2*)&dp[0] = va;
                *(uint2*)&dp[4] = vb;
            }
            __syncthreads();
            bf16x8 ah[4];
#pragma unroll
            for (int rt = 0; rt < 4; ++rt)
                ah[rt] = frag_ld(&As[(rt * 16 + l16) * 36 + kg * 8]);
#pragma unroll
            for (int ct = 0; ct < 4; ++ct) {
                int colf = w * 64 + ct * 16 + l16;
                bf16x8 bh = frag_ld(&Ws[colf * 36 + kg * 8]);
#pragma unroll
                for (int rt = 0; rt < 4; ++rt)
                    hacc[rt][ct] = __builtin_amdgcn_mfma_f32_16x16x32_bf16(ah[rt], bh, hacc[rt][ct], 0, 0, 0);
            }
        }
        // ---- elu -> Hs (bf16) ----
        __syncthreads();
#pragma unroll
        for (int ct = 0; ct < 4; ++ct) {
            int colh = w * 64 + ct * 16 + l16;
#pragma unroll
            for (int rt = 0; rt < 4; ++rt)
#pragma unroll
                for (int reg = 0; reg < 4; ++reg) {
                    int rowL = rt * 16 + kg * 4 + reg;
                    float v = hacc[rt][ct][reg];
                    Hs[rowL * 260 + colh] = f2bf(v > 0.f ? v : expm1f(v));
                }
        }
        __syncthreads();
        // ---- FFN2 partial: oacc += h_chunk @ w2[fc*256.., :] ----
        for (int kc2 = 0; kc2 < 8; ++kc2) {
            if (kc2) __syncthreads();
#pragma unroll
            for (int i = 0; i < 4; ++i) {   // stage W2 chunk
                int idx = i * 256 + tid;
                int col = idx >> 2, part = idx & 3;
                long wsrc = ((long)(fc * 8 + kc2) * 256 + col) * 32 + part * 8;
                uint2 va = *(const uint2*)&W2h[wsrc];
                uint2 vb = *(const uint2*)&W2h[wsrc + 4];
                unsigned short* dp = &Ws[col * 36 + part * 8];
                *(uint2*)&dp[0] = va;
                *(uint2*)&dp[4] = vb;
            }
            __syncthreads();
            bf16x8 ah2[4];
#pragma unroll
            for (int rt = 0; rt < 4; ++rt)
                ah2[rt] = frag_ld(&Hs[(rt * 16 + l16) * 260 + kc2 * 32 + kg * 8]);
#pragma unroll
            for (int ct = 0; ct < 4; ++ct) {
                int colf = w * 64 + ct * 16 + l16;
                bf16x8 bh = frag_ld(&Ws[colf * 36 + kg * 8]);
#pragma unroll
                for (int rt = 0; rt < 4; ++rt)
                    oacc[rt][ct] = __builtin_amdgcn_mfma_f32_16x16x32_bf16(ah2[rt], bh, oacc[rt][ct], 0, 0, 0);
            }
        }
        __syncthreads();   // protect Hs/Ws before next fc overwrites
    }
    // ---- LayerNorm over 256 cols ----
#pragma unroll
    for (int rt = 0; rt < 4; ++rt)
#pragma unroll
        for (int reg = 0; reg < 4; ++reg) {
            float s1 = oacc[rt][0][reg] + oacc[rt][1][reg] + oacc[rt][2][reg] + oacc[rt][3][reg];
            float s2 = oacc[rt][0][reg] * oacc[rt][0][reg] + oacc[rt][1][reg] * oacc[rt][1][reg]
                     + oacc[rt][2][reg] * oacc[rt][2][reg] + oacc[rt][3][reg] * oacc[rt][3][reg];
#pragma unroll
            for (int m = 1; m < 16; m <<= 1) {
                s1 += __shfl_xor(s1, m);
                s2 += __shfl_xor(s2, m);
            }
            int rowL = rt * 16 + kg * 4 + reg;
            if (l16 == 0) { red1[rowL][w] = s1; red2[rowL][w] = s2; }
        }
    __syncthreads();
#pragma unroll
    for (int rt = 0; rt < 4; ++rt)
#pragma unroll
        for (int reg = 0; reg < 4; ++reg) {
            int rowL = rt * 16 + kg * 4 + reg;
            float S1 = red1[rowL][0] + red1[rowL][1] + red1[rowL][2] + red1[rowL][3];
            float S2 = red2[rowL][0] + red2[rowL][1] + red2[rowL][2] + red2[rowL][3];
            float mu = S1 * (1.0f / 256.0f);
            float var = fmaxf(S2 * (1.0f / 256.0f) - mu * mu, 0.0f);
            float rstd = rsqrtf(var + 1e-6f);
#pragma unroll
            for (int ct = 0; ct < 4; ++ct) {
                int col = w * 64 + ct * 16 + l16;
                out[(long)(row0 + rowL) * 256 + col] =
                    (oacc[rt][ct][reg] - mu) * rstd * lng[col] + lnb[col];
            }
        }
}

extern "C" void kernel_launch(void* const* d_in, const int* in_sizes, int n_in,
                              void* d_out, int out_size, void* d_ws, size_t ws_size,
                              hipStream_t stream)
{
    const float* x = (const float*)d_in[0];
    const float* enc = (const float*)d_in[1];
    const float* m1_qw = (const float*)d_in[2];
    const float* m1_qb = (const float*)d_in[3];
    const float* m1_kw = (const float*)d_in[4];
    const float* m1_kb = (const float*)d_in[5];
    const float* m1_vw = (const float*)d_in[6];
    const float* m1_vb = (const float*)d_in[7];
    const float* m1_ow = (const float*)d_in[8];
    const float* m1_ob = (const float*)d_in[9];
    const float* m1_feat = (const float*)d_in[10];
    const float* m2_qw = (const float*)d_in[11];
    const float* m2_qb = (const float*)d_in[12];
    const float* m2_kw = (const float*)d_in[13];
    const float* m2_kb = (const float*)d_in[14];
    const float* m2_vw = (const float*)d_in[15];
    const float* m2_vb = (const float*)d_in[16];
    const float* m2_ow = (const float*)d_in[17];
    const float* m2_ob = (const float*)d_in[18];
    const float* m2_feat = (const float*)d_in[19];
    const float* ffn_w1 = (const float*)d_in[20];
    const float* ffn_b1 = (const float*)d_in[21];
    const float* ffn_w2 = (const float*)d_in[22];
    const float* ffn_b2 = (const float*)d_in[23];
    const float* ln1_g = (const float*)d_in[24];
    const float* ln1_b = (const float*)d_in[25];
    const float* ln2_g = (const float*)d_in[26];
    const float* ln2_b = (const float*)d_in[27];
    const float* ln3_g = (const float*)d_in[28];
    const float* ln3_b = (const float*)d_in[29];

    // round-1 proven layout (span 22,954,496 floats = 91.8 MB)
    float* ws = (float*)d_ws;
    float* pq = ws;                        // 1,638,400
    float* pk = pq + 1638400;              // 1,638,400
    float* v = pk + 1638400;               // 6,553,600
    float* kv1 = v + 6553600;              // 8192
    float* ps1 = kv1 + 8192;               // 256
    float* kv2 = ps1 + 256;                // 8192
    float* ps2 = kv2 + 8192;               // 256
    float* out1 = ps2 + 256;               // 6,553,600
    float* out2 = out1 + 6553600;          // 6,553,600
    float* out3 = (float*)d_out;
    // FFN bf16 packs live in pq's region (pq dead after module 2's attn_out_ln_k;
    // prep_w_k runs after that point). 524,288 ush = 262,144 floats < 1,638,400.
    unsigned short* w1h = (unsigned short*)pq;   // 262,144 ush
    unsigned short* w2h = w1h + 262144;          // 262,144 ush

    hipMemsetAsync(kv1, 0, (8192 + 256) * 2 * sizeof(float), stream);

    // ---- module 1 (self-attention) ----
    qkv_phi_k<<<800, 256, 0, stream>>>(x, x, m1_qw, m1_qb, m1_kw, m1_kb, m1_vw, m1_vb,
                                       m1_feat, pq, pk, v);
    kv_reduce_k<<<800, 256, 0, stream>>>(pk, v, kv1, ps1);
    attn_out_ln_k<<<800, 256, 0, stream>>>(pq, kv1, ps1, m1_ow, m1_ob, x, ln1_g, ln1_b, out1);
    // ---- module 2 (cross-attention) ----
    qkv_phi_k<<<800, 256, 0, stream>>>(out1, enc, m2_qw, m2_qb, m2_kw, m2_kb, m2_vw, m2_vb,
                                       m2_feat, pq, pk, v);
    kv_reduce_k<<<800, 256, 0, stream>>>(pk, v, kv2, ps2);
    attn_out_ln_k<<<800, 256, 0, stream>>>(pq, kv2, ps2, m2_ow, m2_ob, out1, ln2_g, ln2_b, out2);
    // ---- pack FFN weights (pq now dead), then fused MFMA FFN + LN3 ----
    prep_w_k<<<256, 256, 0, stream>>>(ffn_w1, ffn_w2, w1h, w2h);
    ffn_k<<<400, 256, 0, stream>>>(out2, w1h, w2h, ffn_b1, ffn_b2, ln3_g, ln3_b, out3);
}

// Round 9
// 738.945 us; speedup vs baseline: 3.2574x; 1.9908x over previous
//
#include <hip/hip_runtime.h>
#include <math.h>

// Round 9 (= round 8 resubmit; never ran due to GPU timeout).
// QKV projections -> proven MFMA pattern with fused phi epilogue.
// - qkv_mfma_k: grid (400, 3). y=0: q=x@qw (scaled)->LDS->phi->pq. y=1: k->phi->pk.
//   y=2: v fp32 -> global (round-1 layout). Single-bf16 A staging (proven in ffn_k).
// - attention packs (qw|kw|vw -> [8][768][32] bf16) live in out2 region (dead till m2 attn_out).
// - kv_reduce / attn_out_ln stay round-1 fp32 (proven). ffn_k/prep_w_k = round-7 verbatim.
// ws span = round-7's proven 91.8 MB.

#define NSEQ 6400

typedef __attribute__((ext_vector_type(8))) short bf16x8;
typedef __attribute__((ext_vector_type(4))) float f32x4;

__device__ __forceinline__ unsigned short f2bf(float f) {
    unsigned u = __float_as_uint(f);
    return (unsigned short)((u + 0x7fffu + ((u >> 16) & 1u)) >> 16);
}

__device__ __forceinline__ bf16x8 frag_ld(const unsigned short* __restrict__ p) {
    union { uint2 u[2]; bf16x8 v; } x;
    x.u[0] = *(const uint2*)&p[0];
    x.u[1] = *(const uint2*)&p[4];
    return x.v;
}

// ================= round-1 proven fp32 helpers (attn_out path) =================

__device__ __forceinline__ void gemm256(const float* __restrict__ W, int ldw, int colbase,
                                        const float* __restrict__ a_lds, float* __restrict__ w_lds,
                                        float (&acc)[8][4])
{
    const int tid = threadIdx.x;
    const int c0 = (tid & 63) * 4;
    const int rbase = (tid >> 6) * 8;
    for (int ch = 0; ch < 16; ++ch) {
        __syncthreads();
#pragma unroll
        for (int i = 0; i < 4; ++i) {
            int j = i * 1024 + tid * 4;
            int wr = j >> 8, wc = j & 255;
            *(float4*)&w_lds[j] = *(const float4*)&W[(ch * 16 + wr) * ldw + colbase + wc];
        }
        __syncthreads();
#pragma unroll
        for (int kk = 0; kk < 16; kk += 4) {
            float4 w0 = *(const float4*)&w_lds[(kk + 0) * 256 + c0];
            float4 w1 = *(const float4*)&w_lds[(kk + 1) * 256 + c0];
            float4 w2 = *(const float4*)&w_lds[(kk + 2) * 256 + c0];
            float4 w3 = *(const float4*)&w_lds[(kk + 3) * 256 + c0];
#pragma unroll
            for (int r = 0; r < 8; ++r) {
                float4 av = *(const float4*)&a_lds[(rbase + r) * 256 + ch * 16 + kk];
                acc[r][0] += av.x * w0.x + av.y * w1.x + av.z * w2.x + av.w * w3.x;
                acc[r][1] += av.x * w0.y + av.y * w1.y + av.z * w2.y + av.w * w3.y;
                acc[r][2] += av.x * w0.z + av.y * w1.z + av.z * w2.z + av.w * w3.z;
                acc[r][3] += av.x * w0.w + av.y * w1.w + av.z * w2.w + av.w * w3.w;
            }
        }
    }
}

__device__ __forceinline__ void ln_store(float (&acc)[8][4], const float* __restrict__ g,
                                         const float* __restrict__ bb, float* __restrict__ out,
                                         int row0, int rbase, int c0)
{
    float4 gv = *(const float4*)&g[c0];
    float4 bv = *(const float4*)&bb[c0];
#pragma unroll
    for (int r = 0; r < 8; ++r) {
        float v0 = acc[r][0], v1 = acc[r][1], v2 = acc[r][2], v3 = acc[r][3];
        float s1 = v0 + v1 + v2 + v3;
        float s2 = v0 * v0 + v1 * v1 + v2 * v2 + v3 * v3;
#pragma unroll
        for (int off = 1; off < 64; off <<= 1) {
            s1 += __shfl_xor(s1, off);
            s2 += __shfl_xor(s2, off);
        }
        float mu = s1 * (1.0f / 256.0f);
        float var = fmaxf(s2 * (1.0f / 256.0f) - mu * mu, 0.0f);
        float rstd = rsqrtf(var + 1e-6f);
        float4 o;
        o.x = (v0 - mu) * rstd * gv.x + bv.x;
        o.y = (v1 - mu) * rstd * gv.y + bv.y;
        o.z = (v2 - mu) * rstd * gv.z + bv.z;
        o.w = (v3 - mu) * rstd * gv.w + bv.w;
        *(float4*)&out[(long)(row0 + rbase + r) * 256 + c0] = o;
    }
}

// ================= attention weight pack (qw|kw|vw -> [8][768][32] bf16) =================
__global__ __launch_bounds__(256) void prep_aw_k(
    const float* __restrict__ qw1, const float* __restrict__ kw1, const float* __restrict__ vw1,
    const float* __restrict__ qw2, const float* __restrict__ kw2, const float* __restrict__ vw2,
    unsigned short* __restrict__ qkv1h, unsigned short* __restrict__ qkv2h)
{
    __shared__ float wt[32][65];
    const int tid = threadIdx.x;
    const int id = blockIdx.x;            // 192 blocks: 2 modules x 3 srcs x 32
    const int s = (id % 96) / 32, lid = id % 32;
    const float* src;
    unsigned short* dh;
    if (id < 96) { dh = qkv1h; src = (s == 0) ? qw1 : (s == 1) ? kw1 : vw1; }
    else         { dh = qkv2h; src = (s == 0) ? qw2 : (s == 1) ? kw2 : vw2; }
    const int colOff = s * 256, kc = lid >> 2, nb = lid & 3;
    {
        int kr = tid >> 3, nc8 = (tid & 7) * 8;
        const float* sp = &src[(long)(kc * 32 + kr) * 256 + nb * 64 + nc8];
        float4 fa = *(const float4*)&sp[0], fb = *(const float4*)&sp[4];
        wt[kr][nc8 + 0] = fa.x; wt[kr][nc8 + 1] = fa.y; wt[kr][nc8 + 2] = fa.z; wt[kr][nc8 + 3] = fa.w;
        wt[kr][nc8 + 4] = fb.x; wt[kr][nc8 + 5] = fb.y; wt[kr][nc8 + 6] = fb.z; wt[kr][nc8 + 7] = fb.w;
    }
    __syncthreads();
    {
        int col = tid >> 2, part = tid & 3;
        unsigned short hh[8];
#pragma unroll
        for (int j = 0; j < 8; ++j) hh[j] = f2bf(wt[part * 8 + j][col]);
        long di = ((long)kc * 768 + colOff + nb * 64 + col) * 32 + part * 8;
        uint2 a, b;
        a.x = (unsigned)hh[0] | ((unsigned)hh[1] << 16); a.y = (unsigned)hh[2] | ((unsigned)hh[3] << 16);
        b.x = (unsigned)hh[4] | ((unsigned)hh[5] << 16); b.y = (unsigned)hh[6] | ((unsigned)hh[7] << 16);
        *(uint2*)&dh[di] = a;
        *(uint2*)&dh[di + 4] = b;
    }
}

// ================= MFMA QKV projection with fused phi =================
// y=0: q = (Aq@qw + qb)*s -> phi -> pq.  y=1: k from Akv -> phi -> pk.  y=2: v fp32 -> vout.
__global__ __launch_bounds__(256, 2) void qkv_mfma_k(
    const float* __restrict__ Aq, const float* __restrict__ Akv,
    const unsigned short* __restrict__ Wp,   // [8][768][32] bf16 pack
    const float* __restrict__ qb, const float* __restrict__ kb, const float* __restrict__ vb,
    const float* __restrict__ feat,
    float* __restrict__ pq, float* __restrict__ pk, float* __restrict__ vout)
{
    __shared__ float smem[64 * 257];         // union: As+Ws bf16 staging | q_s fp32 [64][257]
    __shared__ float feat_s[32 * 9];
    unsigned short* As = (unsigned short*)smem;      // 64*36 ush
    unsigned short* Ws = As + 64 * 36;               // 256*36 ush
    float* q_s = smem;
    const int tid = threadIdx.x;
    const int row0 = blockIdx.x * 64;
    const int y = blockIdx.y;
    const float* A = (y == 0) ? Aq : Akv;
    const float* bias = (y == 0) ? qb : (y == 1) ? kb : vb;
    const int w = tid >> 6, lane = tid & 63;
    const int l16 = lane & 15, kg = lane >> 4;
    const int st_row = tid >> 2, st_part = tid & 3;
    feat_s[(tid >> 3) * 9 + (tid & 7)] = feat[tid];

    f32x4 acc[4][4];
#pragma unroll
    for (int rt = 0; rt < 4; ++rt)
#pragma unroll
        for (int ct = 0; ct < 4; ++ct) acc[rt][ct] = (f32x4)(0.0f);

    for (int kc = 0; kc < 8; ++kc) {
        __syncthreads();
        {   // stage A (fp32 -> single bf16)   [proven in ffn_k]
            const float* sp = &A[(long)(row0 + st_row) * 256 + kc * 32 + st_part * 8];
            float f[8];
            *(float4*)&f[0] = *(const float4*)&sp[0];
            *(float4*)&f[4] = *(const float4*)&sp[4];
            unsigned short h8[8];
#pragma unroll
            for (int j = 0; j < 8; ++j) h8[j] = f2bf(f[j]);
            uint2 a, b;
            a.x = (unsigned)h8[0] | ((unsigned)h8[1] << 16); a.y = (unsigned)h8[2] | ((unsigned)h8[3] << 16);
            b.x = (unsigned)h8[4] | ((unsigned)h8[5] << 16); b.y = (unsigned)h8[6] | ((unsigned)h8[7] << 16);
            unsigned short* dp = &As[st_row * 36 + st_part * 8];
            *(uint2*)&dp[0] = a;
            *(uint2*)&dp[4] = b;
        }
#pragma unroll
        for (int i = 0; i < 4; ++i) {   // stage W panel chunk from pack
            int idx = i * 256 + tid;
            int col = idx >> 2, part = idx & 3;
            long wsrc = ((long)kc * 768 + y * 256 + col) * 32 + part * 8;
            uint2 va = *(const uint2*)&Wp[wsrc];
            uint2 vb2 = *(const uint2*)&Wp[wsrc + 4];
            unsigned short* dp = &Ws[col * 36 + part * 8];
            *(uint2*)&dp[0] = va;
            *(uint2*)&dp[4] = vb2;
        }
        __syncthreads();
        bf16x8 ah[4];
#pragma unroll
        for (int rt = 0; rt < 4; ++rt)
            ah[rt] = frag_ld(&As[(rt * 16 + l16) * 36 + kg * 8]);
#pragma unroll
        for (int ct = 0; ct < 4; ++ct) {
            int colf = w * 64 + ct * 16 + l16;
            bf16x8 bh = frag_ld(&Ws[colf * 36 + kg * 8]);
#pragma unroll
            for (int rt = 0; rt < 4; ++rt)
                acc[rt][ct] = __builtin_amdgcn_mfma_f32_16x16x32_bf16(ah[rt], bh, acc[rt][ct], 0, 0, 0);
        }
    }

    if (y == 2) {
        // v: bias + write fp32 (round-1 v layout [25600][256])
#pragma unroll
        for (int ct = 0; ct < 4; ++ct) {
            int col = w * 64 + ct * 16 + l16;
            float bv = bias[col];
#pragma unroll
            for (int rt = 0; rt < 4; ++rt)
#pragma unroll
                for (int reg = 0; reg < 4; ++reg) {
                    int row = row0 + rt * 16 + kg * 4 + reg;
                    vout[(long)row * 256 + col] = acc[rt][ct][reg] + bv;
                }
        }
        return;
    }

    // q/k: scale, park in LDS, fused phi
    const float qscale = 0.42044820762685725f;
    const float phin = 0.35355339059327373f;
    __syncthreads();   // all MFMA reads of As/Ws done before q_s overwrites them
#pragma unroll
    for (int ct = 0; ct < 4; ++ct) {
        int col = w * 64 + ct * 16 + l16;
        float bv = bias[col];
#pragma unroll
        for (int rt = 0; rt < 4; ++rt)
#pragma unroll
            for (int reg = 0; reg < 4; ++reg) {
                int rowL = rt * 16 + kg * 4 + reg;
                q_s[rowL * 257 + col] = (acc[rt][ct][reg] + bv) * qscale;
            }
    }
    __syncthreads();
    const int b = row0 / NSEQ;
    const int n0 = row0 % NSEQ;
#pragma unroll
    for (int i = 0; i < 16; ++i) {
        int T = tid + 256 * i;          // 4096 tasks: 64 rows x 8 h x 8 m
        int r = T >> 6, h = (T >> 3) & 7, m = T & 7;
        float dot = 0.f, nrm = 0.f;
#pragma unroll
        for (int k = 0; k < 32; ++k) {
            int kk = (k + 4 * h) & 31;
            float qv = q_s[r * 257 + h * 32 + kk];
            dot += qv * feat_s[kk * 9 + m];
            nrm += qv * qv;
        }
        float o = expf(dot - 0.5f * nrm) * phin;
        if (y == 0) {
            pq[(long)(row0 + r) * 64 + h * 8 + m] = o;
        } else {
            pk[((long)(b * 8 + h) * NSEQ + n0 + r) * 8 + m] = o;
        }
    }
}

// ================= round-1 proven: kv_reduce + attn_out_ln =================

__global__ __launch_bounds__(256) void kv_reduce_k(
    const float* __restrict__ pk,
    const float* __restrict__ v,
    float* __restrict__ kvg,
    float* __restrict__ psg)
{
    const int blk = blockIdx.x;
    const int bh = blk / 25, ch = blk % 25;
    const int b = bh >> 3, h = bh & 7;
    const int n0 = ch * 256;
    const int tid = threadIdx.x;
    const int m = tid >> 5, k = tid & 31;
    const float* pkp = pk + ((long)bh * NSEQ + n0) * 8 + m;
    const float* vp = v + ((long)b * NSEQ + n0) * 256 + h * 32 + k;
    float acc = 0.f, ps = 0.f;
#pragma unroll 4
    for (int n = 0; n < 256; ++n) {
        float pkv = pkp[n * 8];
        float vv = vp[n * 256];
        acc += pkv * vv;
        ps += pkv;
    }
    atomicAdd(&kvg[(bh * 8 + m) * 32 + k], acc);
    if (k == 0) atomicAdd(&psg[bh * 8 + m], ps);
}

__global__ __launch_bounds__(256) void attn_out_ln_k(
    const float* __restrict__ pq,
    const float* __restrict__ kvg,
    const float* __restrict__ psg,
    const float* __restrict__ ow, const float* __restrict__ ob,
    const float* __restrict__ resid,
    const float* __restrict__ g, const float* __restrict__ bb,
    float* __restrict__ out)
{
    __shared__ float pq_s[32 * 64];
    __shared__ float kv_s[2048];
    __shared__ float ps_s[64];
    __shared__ float z_s[32 * 8];
    __shared__ float attn_s[32 * 256];
    __shared__ float w_s[16 * 256];
    const int tid = threadIdx.x;
    const int row0 = blockIdx.x * 32;
    const int b = row0 / NSEQ;
    const int c0 = (tid & 63) * 4, rbase = (tid >> 6) * 8;

    *(float4*)&pq_s[tid * 8] = *(const float4*)&pq[(long)row0 * 64 + tid * 8];
    *(float4*)&pq_s[tid * 8 + 4] = *(const float4*)&pq[(long)row0 * 64 + tid * 8 + 4];
    *(float4*)&kv_s[tid * 8] = *(const float4*)&kvg[b * 2048 + tid * 8];
    *(float4*)&kv_s[tid * 8 + 4] = *(const float4*)&kvg[b * 2048 + tid * 8 + 4];
    if (tid < 16) *(float4*)&ps_s[tid * 4] = *(const float4*)&psg[b * 64 + tid * 4];
    __syncthreads();

    {
        int r = tid >> 3, h = tid & 7;
        float d = 1e-6f;
#pragma unroll
        for (int m = 0; m < 8; ++m) d += pq_s[r * 64 + h * 8 + m] * ps_s[h * 8 + m];
        z_s[r * 8 + h] = 1.0f / d;
    }
    __syncthreads();
    {
        int c = tid, h = c >> 5, k = c & 31;
        float kvv[8];
#pragma unroll
        for (int m = 0; m < 8; ++m) kvv[m] = kv_s[(h * 8 + m) * 32 + k];
        for (int r = 0; r < 32; ++r) {
            float d = 0.f;
#pragma unroll
            for (int m = 0; m < 8; ++m) d += pq_s[r * 64 + h * 8 + m] * kvv[m];
            attn_s[r * 256 + c] = d * z_s[r * 8 + h];
        }
    }
    float acc[8][4];
    {
        float4 bv = *(const float4*)&ob[c0];
#pragma unroll
        for (int r = 0; r < 8; ++r) {
            float4 rv = *(const float4*)&resid[(long)(row0 + rbase + r) * 256 + c0];
            acc[r][0] = bv.x + rv.x; acc[r][1] = bv.y + rv.y;
            acc[r][2] = bv.z + rv.z; acc[r][3] = bv.w + rv.w;
        }
    }
    gemm256(ow, 256, 0, attn_s, w_s, acc);
    ln_store(acc, g, bb, out, row0, rbase, c0);
}

// ================= round-7 proven FFN path =================

__global__ __launch_bounds__(256) void prep_w_k(
    const float* __restrict__ w1, const float* __restrict__ w2,
    unsigned short* __restrict__ w1h, unsigned short* __restrict__ w2h)
{
    __shared__ float wt[32][65];
    const int tid = threadIdx.x;
    const int id = blockIdx.x;
    const float* src; unsigned short* dh;
    int Nsrc, kc, nb;
    if (id < 128) {
        src = w1; dh = w1h; Nsrc = 1024;
        kc = id >> 4; nb = id & 15;
    } else {
        int lid = id - 128;
        src = w2; dh = w2h; Nsrc = 256;
        kc = lid >> 2; nb = lid & 3;
    }
    {
        int kr = tid >> 3, nc8 = (tid & 7) * 8;
        const float* sp = &src[(long)(kc * 32 + kr) * Nsrc + nb * 64 + nc8];
        float4 fa = *(const float4*)&sp[0], fb = *(const float4*)&sp[4];
        wt[kr][nc8 + 0] = fa.x; wt[kr][nc8 + 1] = fa.y; wt[kr][nc8 + 2] = fa.z; wt[kr][nc8 + 3] = fa.w;
        wt[kr][nc8 + 4] = fb.x; wt[kr][nc8 + 5] = fb.y; wt[kr][nc8 + 6] = fb.z; wt[kr][nc8 + 7] = fb.w;
    }
    __syncthreads();
    {
        int col = tid >> 2, part = tid & 3;
        unsigned short hh[8];
#pragma unroll
        for (int j = 0; j < 8; ++j) hh[j] = f2bf(wt[part * 8 + j][col]);
        long di = ((long)kc * Nsrc + nb * 64 + col) * 32 + part * 8;
        uint2 a, b;
        a.x = (unsigned)hh[0] | ((unsigned)hh[1] << 16); a.y = (unsigned)hh[2] | ((unsigned)hh[3] << 16);
        b.x = (unsigned)hh[4] | ((unsigned)hh[5] << 16); b.y = (unsigned)hh[6] | ((unsigned)hh[7] << 16);
        *(uint2*)&dh[di] = a;
        *(uint2*)&dh[di + 4] = b;
    }
}

__global__ __launch_bounds__(256, 2) void ffn_k(
    const float* __restrict__ A,
    const unsigned short* __restrict__ W1h, const unsigned short* __restrict__ W2h,
    const float* __restrict__ b1, const float* __restrict__ b2,
    const float* __restrict__ lng, const float* __restrict__ lnb,
    float* __restrict__ out)
{
    __shared__ unsigned short As[64 * 36];
    __shared__ unsigned short Ws[256 * 36];
    __shared__ unsigned short Hs[64 * 260];
    __shared__ float red1[64][5];
    __shared__ float red2[64][5];
    const int tid = threadIdx.x;
    const int row0 = blockIdx.x * 64;
    const int w = tid >> 6, lane = tid & 63;
    const int l16 = lane & 15, kg = lane >> 4;
    const int st_row = tid >> 2, st_part = tid & 3;

    f32x4 oacc[4][4];
#pragma unroll
    for (int ct = 0; ct < 4; ++ct) {
        int col = w * 64 + ct * 16 + l16;
        float bv = b2[col];
#pragma unroll
        for (int rt = 0; rt < 4; ++rt)
#pragma unroll
            for (int reg = 0; reg < 4; ++reg) {
                int row = row0 + rt * 16 + kg * 4 + reg;
                oacc[rt][ct][reg] = bv + A[(long)row * 256 + col];
            }
    }

    for (int fc = 0; fc < 4; ++fc) {
        f32x4 hacc[4][4];
#pragma unroll
        for (int ct = 0; ct < 4; ++ct) {
            float bv = b1[fc * 256 + w * 64 + ct * 16 + l16];
#pragma unroll
            for (int rt = 0; rt < 4; ++rt) hacc[rt][ct] = (f32x4)(bv);
        }
        for (int kc = 0; kc < 8; ++kc) {
            __syncthreads();
            {
                const float* sp = &A[(long)(row0 + st_row) * 256 + kc * 32 + st_part * 8];
                float f[8];
                *(float4*)&f[0] = *(const float4*)&sp[0];
                *(float4*)&f[4] = *(const float4*)&sp[4];
                unsigned short h8[8];
#pragma unroll
                for (int j = 0; j < 8; ++j) h8[j] = f2bf(f[j]);
                uint2 a, b;
                a.x = (unsigned)h8[0] | ((unsigned)h8[1] << 16); a.y = (unsigned)h8[2] | ((unsigned)h8[3] << 16);
                b.x = (unsigned)h8[4] | ((unsigned)h8[5] << 16); b.y = (unsigned)h8[6] | ((unsigned)h8[7] << 16);
                unsigned short* dp = &As[st_row * 36 + st_part * 8];
                *(uint2*)&dp[0] = a;
                *(uint2*)&dp[4] = b;
            }
#pragma unroll
            for (int i = 0; i < 4; ++i) {
                int idx = i * 256 + tid;
                int col = idx >> 2, part = idx & 3;
                long wsrc = ((long)kc * 1024 + fc * 256 + col) * 32 + part * 8;
                uint2 va = *(const uint2*)&W1h[wsrc];
                uint2 vb = *(const uint2*)&W1h[wsrc + 4];
                unsigned short* dp = &Ws[col * 36 + part * 8];
                *(uint2*)&dp[0] = va;
                *(uint2*)&dp[4] = vb;
            }
            __syncthreads();
            bf16x8 ah[4];
#pragma unroll
            for (int rt = 0; rt < 4; ++rt)
                ah[rt] = frag_ld(&As[(rt * 16 + l16) * 36 + kg * 8]);
#pragma unroll
            for (int ct = 0; ct < 4; ++ct) {
                int colf = w * 64 + ct * 16 + l16;
                bf16x8 bh = frag_ld(&Ws[colf * 36 + kg * 8]);
#pragma unroll
                for (int rt = 0; rt < 4; ++rt)
                    hacc[rt][ct] = __builtin_amdgcn_mfma_f32_16x16x32_bf16(ah[rt], bh, hacc[rt][ct], 0, 0, 0);
            }
        }
        __syncthreads();
#pragma unroll
        for (int ct = 0; ct < 4; ++ct) {
            int colh = w * 64 + ct * 16 + l16;
#pragma unroll
            for (int rt = 0; rt < 4; ++rt)
#pragma unroll
                for (int reg = 0; reg < 4; ++reg) {
                    int rowL = rt * 16 + kg * 4 + reg;
                    float v = hacc[rt][ct][reg];
                    Hs[rowL * 260 + colh] = f2bf(v > 0.f ? v : expm1f(v));
                }
        }
        __syncthreads();
        for (int kc2 = 0; kc2 < 8; ++kc2) {
            if (kc2) __syncthreads();
#pragma unroll
            for (int i = 0; i < 4; ++i) {
                int idx = i * 256 + tid;
                int col = idx >> 2, part = idx & 3;
                long wsrc = ((long)(fc * 8 + kc2) * 256 + col) * 32 + part * 8;
                uint2 va = *(const uint2*)&W2h[wsrc];
                uint2 vb = *(const uint2*)&W2h[wsrc + 4];
                unsigned short* dp = &Ws[col * 36 + part * 8];
                *(uint2*)&dp[0] = va;
                *(uint2*)&dp[4] = vb;
            }
            __syncthreads();
            bf16x8 ah2[4];
#pragma unroll
            for (int rt = 0; rt < 4; ++rt)
                ah2[rt] = frag_ld(&Hs[(rt * 16 + l16) * 260 + kc2 * 32 + kg * 8]);
#pragma unroll
            for (int ct = 0; ct < 4; ++ct) {
                int colf = w * 64 + ct * 16 + l16;
                bf16x8 bh = frag_ld(&Ws[colf * 36 + kg * 8]);
#pragma unroll
                for (int rt = 0; rt < 4; ++rt)
                    oacc[rt][ct] = __builtin_amdgcn_mfma_f32_16x16x32_bf16(ah2[rt], bh, oacc[rt][ct], 0, 0, 0);
            }
        }
        __syncthreads();
    }
#pragma unroll
    for (int rt = 0; rt < 4; ++rt)
#pragma unroll
        for (int reg = 0; reg < 4; ++reg) {
            float s1 = oacc[rt][0][reg] + oacc[rt][1][reg] + oacc[rt][2][reg] + oacc[rt][3][reg];
            float s2 = oacc[rt][0][reg] * oacc[rt][0][reg] + oacc[rt][1][reg] * oacc[rt][1][reg]
                     + oacc[rt][2][reg] * oacc[rt][2][reg] + oacc[rt][3][reg] * oacc[rt][3][reg];
#pragma unroll
            for (int m = 1; m < 16; m <<= 1) {
                s1 += __shfl_xor(s1, m);
                s2 += __shfl_xor(s2, m);
            }
            int rowL = rt * 16 + kg * 4 + reg;
            if (l16 == 0) { red1[rowL][w] = s1; red2[rowL][w] = s2; }
        }
    __syncthreads();
#pragma unroll
    for (int rt = 0; rt < 4; ++rt)
#pragma unroll
        for (int reg = 0; reg < 4; ++reg) {
            int rowL = rt * 16 + kg * 4 + reg;
            float S1 = red1[rowL][0] + red1[rowL][1] + red1[rowL][2] + red1[rowL][3];
            float S2 = red2[rowL][0] + red2[rowL][1] + red2[rowL][2] + red2[rowL][3];
            float mu = S1 * (1.0f / 256.0f);
            float var = fmaxf(S2 * (1.0f / 256.0f) - mu * mu, 0.0f);
            float rstd = rsqrtf(var + 1e-6f);
#pragma unroll
            for (int ct = 0; ct < 4; ++ct) {
                int col = w * 64 + ct * 16 + l16;
                out[(long)(row0 + rowL) * 256 + col] =
                    (oacc[rt][ct][reg] - mu) * rstd * lng[col] + lnb[col];
            }
        }
}

extern "C" void kernel_launch(void* const* d_in, const int* in_sizes, int n_in,
                              void* d_out, int out_size, void* d_ws, size_t ws_size,
                              hipStream_t stream)
{
    const float* x = (const float*)d_in[0];
    const float* enc = (const float*)d_in[1];
    const float* m1_qw = (const float*)d_in[2];
    const float* m1_qb = (const float*)d_in[3];
    const float* m1_kw = (const float*)d_in[4];
    const float* m1_kb = (const float*)d_in[5];
    const float* m1_vw = (const float*)d_in[6];
    const float* m1_vb = (const float*)d_in[7];
    const float* m1_ow = (const float*)d_in[8];
    const float* m1_ob = (const float*)d_in[9];
    const float* m1_feat = (const float*)d_in[10];
    const float* m2_qw = (const float*)d_in[11];
    const float* m2_qb = (const float*)d_in[12];
    const float* m2_kw = (const float*)d_in[13];
    const float* m2_kb = (const float*)d_in[14];
    const float* m2_vw = (const float*)d_in[15];
    const float* m2_vb = (const float*)d_in[16];
    const float* m2_ow = (const float*)d_in[17];
    const float* m2_ob = (const float*)d_in[18];
    const float* m2_feat = (const float*)d_in[19];
    const float* ffn_w1 = (const float*)d_in[20];
    const float* ffn_b1 = (const float*)d_in[21];
    const float* ffn_w2 = (const float*)d_in[22];
    const float* ffn_b2 = (const float*)d_in[23];
    const float* ln1_g = (const float*)d_in[24];
    const float* ln1_b = (const float*)d_in[25];
    const float* ln2_g = (const float*)d_in[26];
    const float* ln2_b = (const float*)d_in[27];
    const float* ln3_g = (const float*)d_in[28];
    const float* ln3_b = (const float*)d_in[29];

    // round-1/7 proven layout (span 91.8 MB)
    float* ws = (float*)d_ws;
    float* pq = ws;                        // 1,638,400
    float* pk = pq + 1638400;              // 1,638,400
    float* v = pk + 1638400;               // 6,553,600
    float* kv1 = v + 6553600;              // 8192
    float* ps1 = kv1 + 8192;               // 256
    float* kv2 = ps1 + 256;                // 8192
    float* ps2 = kv2 + 8192;               // 256
    float* out1 = ps2 + 256;               // 6,553,600
    float* out2 = out1 + 6553600;          // 6,553,600
    float* out3 = (float*)d_out;
    // attention qkv packs live in out2's region (dead until m2's attn_out_ln_k,
    // which runs after both packs are consumed). 393,216 ush << 6.5M floats.
    unsigned short* qkv1h = (unsigned short*)out2;   // 196,608 ush
    unsigned short* qkv2h = qkv1h + 196608;          // 196,608 ush
    // FFN packs in pq region (pq dead after m2's attn_out_ln_k; prep runs then).
    unsigned short* w1h = (unsigned short*)pq;       // 262,144 ush
    unsigned short* w2h = w1h + 262144;              // 262,144 ush

    hipMemsetAsync(kv1, 0, (8192 + 256) * 2 * sizeof(float), stream);
    prep_aw_k<<<192, 256, 0, stream>>>(m1_qw, m1_kw, m1_vw, m2_qw, m2_kw, m2_vw,
                                       qkv1h, qkv2h);

    // ---- module 1 (self-attention) ----
    qkv_mfma_k<<<dim3(400, 3), 256, 0, stream>>>(x, x, qkv1h, m1_qb, m1_kb, m1_vb,
                                                 m1_feat, pq, pk, v);
    kv_reduce_k<<<800, 256, 0, stream>>>(pk, v, kv1, ps1);
    attn_out_ln_k<<<800, 256, 0, stream>>>(pq, kv1, ps1, m1_ow, m1_ob, x, ln1_g, ln1_b, out1);
    // ---- module 2 (cross-attention) ----
    qkv_mfma_k<<<dim3(400, 3), 256, 0, stream>>>(out1, enc, qkv2h, m2_qb, m2_kb, m2_vb,
                                                 m2_feat, pq, pk, v);
    kv_reduce_k<<<800, 256, 0, stream>>>(pk, v, kv2, ps2);
    attn_out_ln_k<<<800, 256, 0, stream>>>(pq, kv2, ps2, m2_ow, m2_ob, out1, ln2_g, ln2_b, out2);
    // ---- pack FFN weights (pq now dead), then fused MFMA FFN + LN3 ----
    prep_w_k<<<256, 256, 0, stream>>>(ffn_w1, ffn_w2, w1h, w2h);
    ffn_k<<<400, 256, 0, stream>>>(out2, w1h, w2h, ffn_b1, ffn_b2, ln3_g, ln3_b, out3);
}